// Round 9
// baseline (229.615 us; speedup 1.0000x reference)
//
#include <hip/hip_runtime.h>
#include <hip/hip_bf16.h>
#include <hip/hip_cooperative_groups.h>
namespace cg = cooperative_groups;

#define B_ 16
#define N_ 1024
#define F_ 16
#define E_ 12
#define H_ 4

// workspace layout (float offsets)
#define OFF_MEANP 0        // 4096: mean partial sums [side*16+b][chunk8][16]
#define OFF_STATS 4096     // 256:  kabsch stats [b][16]         (zeroed in P0)
#define OFF_MOMS  4352     // 5120: self moments [unit128][40]   (zeroed in P0)
#define OFF_MOMC  9472     // 2560: cross moments [unit64][40]   (zeroed in P0)
#define OFF_X3    12032    // 49152: centered x[:, :3]
#define OFF_QS    61184    // 393216: self Q planes [unit128][3][1024]
#define OFF_QC    454400   // 196608: cross Q planes [unit64][3][1024]

// moment layout per unit (39 used, stride 40):
// [0:3]=Sum k | [3:9]=Sum kk (00,11,22,01,02,12) | [9:12]=Sum v
// [12:21]=Sum k_i v_c | [21:39]=Sum kk_pair v_c

__device__ __forceinline__ void mom_compute(float k0, float k1, float k2,
                                            float v0, float v1, float v2, float* m) {
  m[0]=k0; m[1]=k1; m[2]=k2;
  float s00=k0*k0, s11=k1*k1, s22=k2*k2, s01=k0*k1, s02=k0*k2, s12=k1*k2;
  m[3]=s00; m[4]=s11; m[5]=s22; m[6]=s01; m[7]=s02; m[8]=s12;
  m[9]=v0; m[10]=v1; m[11]=v2;
  m[12]=k0*v0; m[13]=k0*v1; m[14]=k0*v2;
  m[15]=k1*v0; m[16]=k1*v1; m[17]=k1*v2;
  m[18]=k2*v0; m[19]=k2*v1; m[20]=k2*v2;
  m[21]=s00*v0; m[22]=s00*v1; m[23]=s00*v2;
  m[24]=s11*v0; m[25]=s11*v1; m[26]=s11*v2;
  m[27]=s22*v0; m[28]=s22*v1; m[29]=s22*v2;
  m[30]=s01*v0; m[31]=s01*v1; m[32]=s01*v2;
  m[33]=s02*v0; m[34]=s02*v1; m[35]=s02*v2;
  m[36]=s12*v0; m[37]=s12*v1; m[38]=s12*v2;
}

__device__ __forceinline__ void wave_reduce39(float* m) {
#pragma unroll
  for (int i = 0; i < 39; i++) {
    m[i] += __shfl_down(m[i], 32); m[i] += __shfl_down(m[i], 16);
    m[i] += __shfl_down(m[i], 8);  m[i] += __shfl_down(m[i], 4);
    m[i] += __shfl_down(m[i], 2);  m[i] += __shfl_down(m[i], 1);
  }
}

// eval with pre-scaled moments (diag 2nd-order entries x0.5 applied at LDS stage)
__device__ __forceinline__ void attn_eval(const float* __restrict__ mu,
                                          float p0, float p1, float p2, float* out) {
  float pp0=p0*p0, pp1=p1*p1, pp2=p2*p2;
  float q01=p0*p1, q02=p0*p2, q12=p1*p2;
  float den = (float)N_;
  den = fmaf(p0, mu[0], den); den = fmaf(p1, mu[1], den); den = fmaf(p2, mu[2], den);
  den = fmaf(pp0, mu[3], den); den = fmaf(pp1, mu[4], den); den = fmaf(pp2, mu[5], den);
  den = fmaf(q01, mu[6], den); den = fmaf(q02, mu[7], den); den = fmaf(q12, mu[8], den);
  float inv = 1.0f / den;
#pragma unroll
  for (int c = 0; c < 3; c++) {
    float num = mu[9+c];
    num = fmaf(p0, mu[12+c], num); num = fmaf(p1, mu[15+c], num); num = fmaf(p2, mu[18+c], num);
    num = fmaf(pp0, mu[21+c], num); num = fmaf(pp1, mu[24+c], num); num = fmaf(pp2, mu[27+c], num);
    num = fmaf(q01, mu[30+c], num); num = fmaf(q02, mu[33+c], num); num = fmaf(q12, mu[36+c], num);
    out[c] = num * inv;
  }
}

__device__ __forceinline__ float mom_scale(int j) {
  return ((j >= 3 && j < 6) || (j >= 21 && j < 30)) ? 0.5f : 1.0f;
}

// ============ single cooperative kernel: 256 blocks x 128 threads, 5 phases ============
__global__ __launch_bounds__(128, 1)
void k_all(const float* __restrict__ xo, const float* __restrict__ yo,
           const float* __restrict__ W_in, const float* __restrict__ b_in,
           const float* __restrict__ Wqkv_s, const float* __restrict__ bqkv_s,
           const float* __restrict__ Wo_s, const float* __restrict__ bo_s,
           const float* __restrict__ Wqkv_c, const float* __restrict__ bqkv_c,
           const float* __restrict__ Wo_c, const float* __restrict__ bo_c,
           const float* __restrict__ W_out, const float* __restrict__ b_out,
           float* ws, float* out) {
  cg::grid_group grid = cg::this_grid();
  __shared__ float shm[2176];        // LDS arena, re-carved per phase (8.7 KB)
  float* meanp = ws + OFF_MEANP;
  float* stats = ws + OFF_STATS;
  float* momS  = ws + OFF_MOMS;
  float* momC  = ws + OFF_MOMC;
  float* x3    = ws + OFF_X3;
  float* Qs    = ws + OFF_QS;
  float* Qc    = ws + OFF_QC;
  int tid  = threadIdx.x;
  int blk  = blockIdx.x;
  int side = blk >> 7;
  int rem  = blk & 127;
  int b    = rem >> 3, c = rem & 7;
  int wv   = tid >> 6;
  const float SC = 0.57735026918962584f;   // 1/sqrt(3)

  // ---------------- P0: partial means + zero stats/moments ----------------
  if (blk < 62) ws[OFF_STATS + blk*128 + tid] = 0.f;   // 7936 = STATS+MOMS+MOMC contiguous
  {
    int n = c * 128 + tid;
    const float* in = side ? yo : xo;
    float s[F_];
    const float4* p = (const float4*)(in + ((size_t)b * N_ + n) * F_);
#pragma unroll
    for (int q = 0; q < 4; q++) {
      float4 v = p[q];
      s[4*q+0]=v.x; s[4*q+1]=v.y; s[4*q+2]=v.z; s[4*q+3]=v.w;
    }
    float* red = shm;                // 128*17 = 2176
#pragma unroll
    for (int f = 0; f < F_; f++) red[tid*17+f] = s[f];
    __syncthreads();
    for (int st = 64; st > 0; st >>= 1) {
      if (tid < st) {
#pragma unroll
        for (int f = 0; f < F_; f++) red[tid*17+f] += red[(tid+st)*17+f];
      }
      __syncthreads();
    }
    if (tid < F_) meanp[(side*16 + b)*128 + c*16 + tid] = red[tid];
  }
  grid.sync();

  // ---------------- P1: center + W_in + QKV_self -> Q planes + self moments ----------------
  {
    float* sw    = shm;              // 672
    float* smean = shm + 672;        // 16
    float* sred  = shm + 688;        // 2*160
    for (int i = tid; i < 672; i += 128) {
      float v;
      if (i < 192) v = W_in[i];
      else if (i < 204) v = b_in[i - 192];
      else if (i < 636) v = Wqkv_s[i - 204];
      else v = bqkv_s[i - 636];
      sw[i] = v;
    }
    if (tid < F_) {
      float m = 0.f;
#pragma unroll
      for (int cc = 0; cc < 8; cc++) m += meanp[(side*16 + b)*128 + cc*16 + tid];
      smean[tid] = m * (1.0f / N_);
    }
    __syncthreads();
    int n = c * 128 + tid;
    int t = b * N_ + n;
    const float* in = (side ? yo : xo) + (size_t)t * F_;
    float xv[F_];
    {
      const float4* p = (const float4*)in;
#pragma unroll
      for (int q = 0; q < 4; q++) {
        float4 v = p[q];
        xv[4*q+0]=v.x; xv[4*q+1]=v.y; xv[4*q+2]=v.z; xv[4*q+3]=v.w;
      }
    }
#pragma unroll
    for (int f = 0; f < F_; f++) xv[f] -= smean[f];
    if (!side) {
      x3[(size_t)t*3+0]=xv[0]; x3[(size_t)t*3+1]=xv[1]; x3[(size_t)t*3+2]=xv[2];
    }
    float xi[E_];
#pragma unroll
    for (int e = 0; e < E_; e++) {
      float s = sw[192 + e];
#pragma unroll
      for (int f = 0; f < F_; f++) s = fmaf(xv[f], sw[e*F_+f], s);
      xi[e] = s;
    }
    int ub = (side ? 64 : 0) + b * 4;
#pragma unroll
    for (int h = 0; h < H_; h++) {
      float qkv[9];
#pragma unroll
      for (int d = 0; d < 9; d++) {
        int o = (d/3)*12 + h*3 + (d%3);   // q=h*3+c, k=12+h*3+c, v=24+h*3+c
        float s = sw[636 + o];
#pragma unroll
        for (int e = 0; e < E_; e++) s = fmaf(xi[e], sw[204 + o*E_ + e], s);
        qkv[d] = s;
      }
#pragma unroll
      for (int d = 0; d < 3; d++) Qs[(ub + h)*3072 + d*1024 + n] = qkv[d];
      float m[39];
      mom_compute(qkv[3], qkv[4], qkv[5], qkv[6], qkv[7], qkv[8], m);
      wave_reduce39(m);
      if ((tid & 63) == 0) {
#pragma unroll
        for (int j = 0; j < 39; j++) sred[wv*160 + h*40+j] = m[j];
      }
    }
    __syncthreads();
    if (tid < 39) {
#pragma unroll
      for (int h = 0; h < H_; h++)
        atomicAdd(&momS[(ub + h)*40 + tid], sred[h*40+tid] + sred[160 + h*40+tid]);
    }
  }
  grid.sync();

  // ------- P2: self-eval + Wo_s + QKV_cross; x->Qc planes, y->cross moments -------
  {
    float* sw   = shm;               // 624
    float* smu  = shm + 624;         // 160
    float* sred = shm + 784;         // 2*160
    int ub = (side ? 64 : 0) + b * 4;
    for (int i = tid; i < 624; i += 128) {
      float v;
      if (i < 144) v = Wo_s[i];
      else if (i < 156) v = bo_s[i-144];
      else if (i < 588) v = Wqkv_c[i-156];
      else v = bqkv_c[i-588];
      sw[i] = v;
    }
    for (int i = tid; i < 160; i += 128) {
      int h = i / 40, j = i - h*40;
      float v = 0.f;
      if (j < 39) v = momS[(ub + h)*40 + j] * mom_scale(j);
      smu[i] = v;
    }
    __syncthreads();
    int n = c * 128 + tid;
    float attn[E_];
#pragma unroll
    for (int h = 0; h < H_; h++) {
      float p0 = Qs[(ub+h)*3072 + n] * SC;
      float p1 = Qs[(ub+h)*3072 + 1024 + n] * SC;
      float p2 = Qs[(ub+h)*3072 + 2048 + n] * SC;
      attn_eval(&smu[h*40], p0, p1, p2, &attn[h*3]);
    }
    float i2[E_];
#pragma unroll
    for (int e = 0; e < E_; e++) {
      float s = sw[144+e];
#pragma unroll
      for (int j = 0; j < E_; j++) s = fmaf(attn[j], sw[e*E_+j], s);
      i2[e] = s;
    }
    if (!side) {                      // x side -> Q_c planes
#pragma unroll
      for (int h = 0; h < H_; h++)
#pragma unroll
        for (int d = 0; d < 3; d++) {
          int o = h*3 + d;
          float s = sw[588+o];
#pragma unroll
          for (int e = 0; e < E_; e++) s = fmaf(i2[e], sw[156 + o*E_ + e], s);
          Qc[(b*4+h)*3072 + d*1024 + n] = s;
        }
    } else {                          // y side -> cross moments
#pragma unroll
      for (int h = 0; h < H_; h++) {
        float kv[6];
#pragma unroll
        for (int d = 0; d < 6; d++) {
          int o = 12 + (d/3)*12 + h*3 + (d%3);
          float s = sw[588+o];
#pragma unroll
          for (int e = 0; e < E_; e++) s = fmaf(i2[e], sw[156 + o*E_ + e], s);
          kv[d] = s;
        }
        float m[39];
        mom_compute(kv[0], kv[1], kv[2], kv[3], kv[4], kv[5], m);
        wave_reduce39(m);
        if ((tid & 63) == 0) {
#pragma unroll
          for (int j = 0; j < 39; j++) sred[wv*160 + h*40+j] = m[j];
        }
      }
      __syncthreads();                // block-uniform branch (side per block)
      if (tid < 39) {
#pragma unroll
        for (int h = 0; h < H_; h++)
          atomicAdd(&momC[(b*4 + h)*40 + tid], sred[h*40+tid] + sred[160 + h*40+tid]);
      }
    }
  }
  grid.sync();

  // ------- P3: cross-eval + Wo_c + W_out + Kabsch stats (blocks < 128) -------
  if (blk < 128) {
    float* sw    = shm;              // 195
    float* smu   = shm + 195;        // 160
    float* sredK = shm + 355;        // 2*16
    int b3 = blk >> 3, c3 = blk & 7;
    for (int i = tid; i < 195; i += 128) {
      float v;
      if (i < 144) v = Wo_c[i];
      else if (i < 156) v = bo_c[i-144];
      else if (i < 192) v = W_out[i-156];
      else v = b_out[i-192];
      sw[i] = v;
    }
    for (int i = tid; i < 160; i += 128) {
      int h = i / 40, j = i - h*40;
      float v = 0.f;
      if (j < 39) v = momC[(b3*4 + h)*40 + j] * mom_scale(j);
      smu[i] = v;
    }
    __syncthreads();
    int n = c3 * 128 + tid;
    int t = b3 * N_ + n;
    float attn[E_];
#pragma unroll
    for (int h = 0; h < H_; h++) {
      float p0 = Qc[(b3*4+h)*3072 + n] * SC;
      float p1 = Qc[(b3*4+h)*3072 + 1024 + n] * SC;
      float p2 = Qc[(b3*4+h)*3072 + 2048 + n] * SC;
      attn_eval(&smu[h*40], p0, p1, p2, &attn[h*3]);
    }
    float c12[E_];
#pragma unroll
    for (int e = 0; e < E_; e++) {
      float s = sw[144+e];
#pragma unroll
      for (int j = 0; j < E_; j++) s = fmaf(attn[j], sw[e*E_+j], s);
      c12[e] = s;
    }
    float co[3];
#pragma unroll
    for (int k = 0; k < 3; k++) {
      float s = sw[192+k];
#pragma unroll
      for (int e = 0; e < E_; e++) s = fmaf(c12[e], sw[156 + k*E_ + e], s);
      co[k] = s;
    }
    float x0 = x3[(size_t)t*3], x1 = x3[(size_t)t*3+1], x2 = x3[(size_t)t*3+2];
    float A0 = co[0]+x0, A1 = co[1]+x1, A2 = co[2]+x2;
    float st[15];
    st[0]=co[0]; st[1]=co[1]; st[2]=co[2];
    st[3]=x0; st[4]=x1; st[5]=x2;
    st[6]=x0*A0; st[7]=x0*A1; st[8]=x0*A2;
    st[9]=x1*A0; st[10]=x1*A1; st[11]=x1*A2;
    st[12]=x2*A0; st[13]=x2*A1; st[14]=x2*A2;
#pragma unroll
    for (int i = 0; i < 15; i++) {
      st[i] += __shfl_down(st[i], 32); st[i] += __shfl_down(st[i], 16);
      st[i] += __shfl_down(st[i], 8);  st[i] += __shfl_down(st[i], 4);
      st[i] += __shfl_down(st[i], 2);  st[i] += __shfl_down(st[i], 1);
    }
    if ((tid & 63) == 0) {
#pragma unroll
      for (int i = 0; i < 15; i++) sredK[wv*16 + i] = st[i];
    }
    __syncthreads();
    if (tid < 15) atomicAdd(&stats[b3*16 + tid], sredK[tid] + sredK[16 + tid]);
  }
  grid.sync();

  // ------- P4: redundant polar per block + transform (blocks < 128) -------
  if (blk < 128) {
    int b4 = blk >> 3;
    const float* s = stats + b4*16;
    float invN = 1.0f / N_;
    float cB[3] = { s[3]*invN, s[4]*invN, s[5]*invN };
    float cA[3] = { (s[0]+s[3])*invN, (s[1]+s[4])*invN, (s[2]+s[5])*invN };
    float X[9];
#pragma unroll
    for (int i = 0; i < 3; i++)
#pragma unroll
      for (int j = 0; j < 3; j++)
        X[i*3+j] = s[6 + i*3 + j] - (float)N_ * cB[i] * cA[j];
    float fn = 0.f;
#pragma unroll
    for (int i = 0; i < 9; i++) fn += X[i]*X[i];
    float scl = rsqrtf(fn);
#pragma unroll
    for (int i = 0; i < 9; i++) X[i] *= scl;
    for (int it = 0; it < 24; it++) {
      float c00 =  X[4]*X[8]-X[5]*X[7];
      float c01 = -(X[3]*X[8]-X[5]*X[6]);
      float c02 =  X[3]*X[7]-X[4]*X[6];
      float c10 = -(X[1]*X[8]-X[2]*X[7]);
      float c11 =  X[0]*X[8]-X[2]*X[6];
      float c12_= -(X[0]*X[7]-X[1]*X[6]);
      float c20 =  X[1]*X[5]-X[2]*X[4];
      float c21 = -(X[0]*X[5]-X[2]*X[3]);
      float c22 =  X[0]*X[4]-X[1]*X[3];
      float det = X[0]*c00 + X[1]*c01 + X[2]*c02;
      float id = 0.5f / det;
      X[0]=0.5f*X[0]+c00*id; X[1]=0.5f*X[1]+c01*id; X[2]=0.5f*X[2]+c02*id;
      X[3]=0.5f*X[3]+c10*id; X[4]=0.5f*X[4]+c11*id; X[5]=0.5f*X[5]+c12_*id;
      X[6]=0.5f*X[6]+c20*id; X[7]=0.5f*X[7]+c21*id; X[8]=0.5f*X[8]+c22*id;
    }
    float tt[3];
#pragma unroll
    for (int k = 0; k < 3; k++) {
      float m = 0.f;
#pragma unroll
      for (int cc = 0; cc < 8; cc++) m += meanp[(16 + b4)*128 + cc*16 + k];  // y mean
      tt[k] = cA[k] - (cB[0]*X[k] + cB[1]*X[3+k] + cB[2]*X[6+k]) + m * invN;
    }
    size_t t = (size_t)blk * 128 + tid;
    float x0=x3[t*3], x1=x3[t*3+1], x2=x3[t*3+2];
#pragma unroll
    for (int k = 0; k < 3; k++) {
      float v = fmaf(x0, X[k], fmaf(x1, X[3+k], fmaf(x2, X[6+k], tt[k])));
      out[t*3+k] = v;
    }
  }
}

extern "C" void kernel_launch(void* const* d_in, const int* in_sizes, int n_in,
                              void* d_out, int out_size, void* d_ws, size_t ws_size,
                              hipStream_t stream) {
  const float* x_orig = (const float*)d_in[0];
  const float* y_orig = (const float*)d_in[1];
  const float* W_in   = (const float*)d_in[2];
  const float* b_in   = (const float*)d_in[3];
  const float* Wqkv_s = (const float*)d_in[4];
  const float* bqkv_s = (const float*)d_in[5];
  const float* Wo_s   = (const float*)d_in[6];
  const float* bo_s   = (const float*)d_in[7];
  const float* Wqkv_c = (const float*)d_in[8];
  const float* bqkv_c = (const float*)d_in[9];
  const float* Wo_c   = (const float*)d_in[10];
  const float* bo_c   = (const float*)d_in[11];
  const float* W_out  = (const float*)d_in[12];
  const float* b_out  = (const float*)d_in[13];
  float* ws  = (float*)d_ws;
  float* outp = (float*)d_out;

  void* args[] = {
    (void*)&x_orig, (void*)&y_orig, (void*)&W_in, (void*)&b_in,
    (void*)&Wqkv_s, (void*)&bqkv_s, (void*)&Wo_s, (void*)&bo_s,
    (void*)&Wqkv_c, (void*)&bqkv_c, (void*)&Wo_c, (void*)&bo_c,
    (void*)&W_out, (void*)&b_out, (void*)&ws, (void*)&outp
  };
  hipLaunchCooperativeKernel((const void*)k_all, dim3(256), dim3(128),
                             args, 0, stream);
}

// Round 10
// 123.763 us; speedup vs baseline: 1.8553x; 1.8553x over previous
//
#include <hip/hip_runtime.h>
#include <hip/hip_bf16.h>

#define B_ 16
#define N_ 1024
#define F_ 16
#define E_ 12
#define H_ 4

// workspace layout (float offsets)
#define OFF_MEANP 0        // 4096: mean partial sums [side*16+b][chunk8][16]
#define OFF_MOMS  4352     // 5120: self moments [unit128][40]   (zeroed in K0)
#define OFF_MOMC  9472     // 2560: cross moments [unit64][40]   (zeroed in K0)
#define OFF_X3    12032    // 49152: centered x[:, :3]
#define OFF_QS    61184    // 393216: self Q planes [unit128][3][1024]
#define OFF_QC    454400   // 196608: cross Q planes [unit64][3][1024]

// moment layout per unit (39 used, stride 40):
// [0:3]=Sum k | [3:9]=Sum kk (00,11,22,01,02,12) | [9:12]=Sum v
// [12:21]=Sum k_i v_c | [21:39]=Sum kk_pair v_c

__device__ __forceinline__ void mom_compute(float k0, float k1, float k2,
                                            float v0, float v1, float v2, float* m) {
  m[0]=k0; m[1]=k1; m[2]=k2;
  float s00=k0*k0, s11=k1*k1, s22=k2*k2, s01=k0*k1, s02=k0*k2, s12=k1*k2;
  m[3]=s00; m[4]=s11; m[5]=s22; m[6]=s01; m[7]=s02; m[8]=s12;
  m[9]=v0; m[10]=v1; m[11]=v2;
  m[12]=k0*v0; m[13]=k0*v1; m[14]=k0*v2;
  m[15]=k1*v0; m[16]=k1*v1; m[17]=k1*v2;
  m[18]=k2*v0; m[19]=k2*v1; m[20]=k2*v2;
  m[21]=s00*v0; m[22]=s00*v1; m[23]=s00*v2;
  m[24]=s11*v0; m[25]=s11*v1; m[26]=s11*v2;
  m[27]=s22*v0; m[28]=s22*v1; m[29]=s22*v2;
  m[30]=s01*v0; m[31]=s01*v1; m[32]=s01*v2;
  m[33]=s02*v0; m[34]=s02*v1; m[35]=s02*v2;
  m[36]=s12*v0; m[37]=s12*v1; m[38]=s12*v2;
}

__device__ __forceinline__ void wave_reduce39(float* m) {
#pragma unroll
  for (int i = 0; i < 39; i++) {
    m[i] += __shfl_down(m[i], 32); m[i] += __shfl_down(m[i], 16);
    m[i] += __shfl_down(m[i], 8);  m[i] += __shfl_down(m[i], 4);
    m[i] += __shfl_down(m[i], 2);  m[i] += __shfl_down(m[i], 1);
  }
}

// eval with pre-scaled moments (diag 2nd-order entries x0.5 applied at LDS stage)
__device__ __forceinline__ void attn_eval(const float* __restrict__ mu,
                                          float p0, float p1, float p2, float* out) {
  float pp0=p0*p0, pp1=p1*p1, pp2=p2*p2;
  float q01=p0*p1, q02=p0*p2, q12=p1*p2;
  float den = (float)N_;
  den = fmaf(p0, mu[0], den); den = fmaf(p1, mu[1], den); den = fmaf(p2, mu[2], den);
  den = fmaf(pp0, mu[3], den); den = fmaf(pp1, mu[4], den); den = fmaf(pp2, mu[5], den);
  den = fmaf(q01, mu[6], den); den = fmaf(q02, mu[7], den); den = fmaf(q12, mu[8], den);
  float inv = 1.0f / den;
#pragma unroll
  for (int c = 0; c < 3; c++) {
    float num = mu[9+c];
    num = fmaf(p0, mu[12+c], num); num = fmaf(p1, mu[15+c], num); num = fmaf(p2, mu[18+c], num);
    num = fmaf(pp0, mu[21+c], num); num = fmaf(pp1, mu[24+c], num); num = fmaf(pp2, mu[27+c], num);
    num = fmaf(q01, mu[30+c], num); num = fmaf(q02, mu[33+c], num); num = fmaf(q12, mu[36+c], num);
    out[c] = num * inv;
  }
}

__device__ __forceinline__ float mom_scale(int j) {
  return ((j >= 3 && j < 6) || (j >= 21 && j < 30)) ? 0.5f : 1.0f;
}

// ---------------- K0: partial means (256 blocks x 128) + zero moment buffers ----------------
__global__ __launch_bounds__(128, 1)
void k_means(const float* __restrict__ xo, const float* __restrict__ yo,
             float* __restrict__ meanp, float* __restrict__ zbuf) {
  int blk = blockIdx.x;              // side(1)|b(4)|chunk(3)
  int tid = threadIdx.x;
  if (blk < 60) zbuf[blk * 128 + tid] = 0.f;   // 7680 = MOMS(5120)+MOMC(2560) contiguous
  int side = blk >> 7;
  int rem  = blk & 127;
  int b = rem >> 3, c = rem & 7;
  int n = c * 128 + tid;
  const float* in = side ? yo : xo;
  float s[F_];
  {
    const float4* p = (const float4*)(in + ((size_t)b * N_ + n) * F_);
#pragma unroll
    for (int q = 0; q < 4; q++) {
      float4 v = p[q];
      s[4*q+0]=v.x; s[4*q+1]=v.y; s[4*q+2]=v.z; s[4*q+3]=v.w;
    }
  }
  __shared__ float red[128 * 17];
#pragma unroll
  for (int f = 0; f < F_; f++) red[tid*17+f] = s[f];
  __syncthreads();
  for (int st = 64; st > 0; st >>= 1) {
    if (tid < st) {
#pragma unroll
      for (int f = 0; f < F_; f++) red[tid*17+f] += red[(tid+st)*17+f];
    }
    __syncthreads();
  }
  if (tid < F_) meanp[(side*16 + b)*128 + c*16 + tid] = red[tid];
}

// ---------------- K1: center + W_in + QKV_self -> Q planes + self moments ----------------
__global__ __launch_bounds__(128, 1)
void k_proj(const float* __restrict__ xo, const float* __restrict__ yo,
            const float* __restrict__ meanp,
            const float* __restrict__ W_in, const float* __restrict__ b_in,
            const float* __restrict__ Wqkv, const float* __restrict__ bqkv,
            float* __restrict__ x3, float* __restrict__ Qs,
            float* __restrict__ momS) {
  __shared__ float sw[672];          // W_in 192 | b_in 12 | Wqkv_s 432 | bqkv_s 36
  __shared__ float smean[F_];
  __shared__ float sred[2][160];
  int tid = threadIdx.x;
  int blk = blockIdx.x;
  int side = blk >> 7;
  int rem  = blk & 127;
  int b = rem >> 3, c = rem & 7;
  for (int i = tid; i < 672; i += 128) {
    float v;
    if (i < 192) v = W_in[i];
    else if (i < 204) v = b_in[i - 192];
    else if (i < 636) v = Wqkv[i - 204];
    else v = bqkv[i - 636];
    sw[i] = v;
  }
  if (tid < F_) {
    float m = 0.f;
#pragma unroll
    for (int cc = 0; cc < 8; cc++) m += meanp[(side*16 + b)*128 + cc*16 + tid];
    smean[tid] = m * (1.0f / N_);
  }
  __syncthreads();
  int n = c * 128 + tid;
  int t = b * N_ + n;
  const float* in = (side ? yo : xo) + (size_t)t * F_;
  float xv[F_];
  {
    const float4* p = (const float4*)in;
#pragma unroll
    for (int q = 0; q < 4; q++) {
      float4 v = p[q];
      xv[4*q+0]=v.x; xv[4*q+1]=v.y; xv[4*q+2]=v.z; xv[4*q+3]=v.w;
    }
  }
#pragma unroll
  for (int f = 0; f < F_; f++) xv[f] -= smean[f];
  if (!side) {
    x3[(size_t)t*3+0]=xv[0]; x3[(size_t)t*3+1]=xv[1]; x3[(size_t)t*3+2]=xv[2];
  }
  float xi[E_];
#pragma unroll
  for (int e = 0; e < E_; e++) {
    float s = sw[192 + e];
#pragma unroll
    for (int f = 0; f < F_; f++) s = fmaf(xv[f], sw[e*F_+f], s);
    xi[e] = s;
  }
  int ub = (side ? 64 : 0) + b * 4;
  int wv = tid >> 6;
#pragma unroll
  for (int h = 0; h < H_; h++) {
    float qkv[9];
#pragma unroll
    for (int d = 0; d < 9; d++) {
      int o = (d/3)*12 + h*3 + (d%3);   // q=h*3+c, k=12+h*3+c, v=24+h*3+c
      float s = sw[636 + o];
#pragma unroll
      for (int e = 0; e < E_; e++) s = fmaf(xi[e], sw[204 + o*E_ + e], s);
      qkv[d] = s;
    }
#pragma unroll
    for (int d = 0; d < 3; d++) Qs[(ub + h)*3072 + d*1024 + n] = qkv[d];
    float m[39];
    mom_compute(qkv[3], qkv[4], qkv[5], qkv[6], qkv[7], qkv[8], m);
    wave_reduce39(m);
    if ((tid & 63) == 0) {
#pragma unroll
      for (int j = 0; j < 39; j++) sred[wv][h*40+j] = m[j];
    }
  }
  __syncthreads();
  if (tid < 39) {
#pragma unroll
    for (int h = 0; h < H_; h++)
      atomicAdd(&momS[(ub + h)*40 + tid], sred[0][h*40+tid] + sred[1][h*40+tid]);
  }
}

// ---- K2: self-eval + Wo_s + QKV_cross; x->Qc planes, y->cross moments ----
__global__ __launch_bounds__(128, 1)
void k_mid(const float* __restrict__ Qs, const float* __restrict__ momS,
           const float* __restrict__ Wo_s, const float* __restrict__ bo_s,
           const float* __restrict__ Wqkv_c, const float* __restrict__ bqkv_c,
           float* __restrict__ Qc, float* __restrict__ momC) {
  __shared__ float sw[624];          // Wo_s 144 | bo_s 12 | Wqkv_c 432 | bqkv_c 36
  __shared__ float smu[160];
  __shared__ float sred[2][160];
  int tid = threadIdx.x;
  int blk = blockIdx.x;
  int side = blk >> 7;
  int rem  = blk & 127;
  int b = rem >> 3, c = rem & 7;
  int ub = (side ? 64 : 0) + b * 4;
  for (int i = tid; i < 624; i += 128) {
    float v;
    if (i < 144) v = Wo_s[i];
    else if (i < 156) v = bo_s[i-144];
    else if (i < 588) v = Wqkv_c[i-156];
    else v = bqkv_c[i-588];
    sw[i] = v;
  }
  for (int i = tid; i < 160; i += 128) {
    int h = i / 40, j = i - h*40;
    float v = 0.f;
    if (j < 39) v = momS[(ub + h)*40 + j] * mom_scale(j);
    smu[i] = v;
  }
  __syncthreads();
  int n = c * 128 + tid;
  const float SC = 0.57735026918962584f;   // 1/sqrt(3)
  float attn[E_];
#pragma unroll
  for (int h = 0; h < H_; h++) {
    float p0 = Qs[(ub+h)*3072 + n] * SC;
    float p1 = Qs[(ub+h)*3072 + 1024 + n] * SC;
    float p2 = Qs[(ub+h)*3072 + 2048 + n] * SC;
    attn_eval(&smu[h*40], p0, p1, p2, &attn[h*3]);
  }
  float i2[E_];
#pragma unroll
  for (int e = 0; e < E_; e++) {
    float s = sw[144+e];
#pragma unroll
    for (int j = 0; j < E_; j++) s = fmaf(attn[j], sw[e*E_+j], s);
    i2[e] = s;
  }
  if (!side) {                        // x side -> Q_c planes
#pragma unroll
    for (int h = 0; h < H_; h++)
#pragma unroll
      for (int d = 0; d < 3; d++) {
        int o = h*3 + d;
        float s = sw[588+o];
#pragma unroll
        for (int e = 0; e < E_; e++) s = fmaf(i2[e], sw[156 + o*E_ + e], s);
        Qc[(b*4+h)*3072 + d*1024 + n] = s;
      }
  } else {                            // y side -> cross moments
    int wv = tid >> 6;
#pragma unroll
    for (int h = 0; h < H_; h++) {
      float kv[6];
#pragma unroll
      for (int d = 0; d < 6; d++) {
        int o = 12 + (d/3)*12 + h*3 + (d%3);
        float s = sw[588+o];
#pragma unroll
        for (int e = 0; e < E_; e++) s = fmaf(i2[e], sw[156 + o*E_ + e], s);
        kv[d] = s;
      }
      float m[39];
      mom_compute(kv[0], kv[1], kv[2], kv[3], kv[4], kv[5], m);
      wave_reduce39(m);
      if ((tid & 63) == 0) {
#pragma unroll
        for (int j = 0; j < 39; j++) sred[wv][h*40+j] = m[j];
      }
    }
    __syncthreads();                  // block-uniform branch (side per block)
    if (tid < 39) {
#pragma unroll
      for (int h = 0; h < H_; h++)
        atomicAdd(&momC[(b*4 + h)*40 + tid], sred[0][h*40+tid] + sred[1][h*40+tid]);
    }
  }
}

// ---- K3: cross-eval + Wo_c + W_out + in-block Kabsch stats + polar + transform ----
// 16 blocks x 256 threads; block owns batch b; 4 tokens/thread.
__global__ __launch_bounds__(256, 1)
void k_fin(const float* __restrict__ Qc, const float* __restrict__ momC,
           const float* __restrict__ x3, const float* __restrict__ meanp,
           const float* __restrict__ Wo_c, const float* __restrict__ bo_c,
           const float* __restrict__ W_out, const float* __restrict__ b_out,
           float* __restrict__ out) {
  __shared__ float sw[195];          // Wo_c 144 | bo_c 12 | W_out 36 | b_out 3
  __shared__ float smu[160];
  __shared__ float sred[4][16];
  __shared__ float sstats[16];
  int tid = threadIdx.x;
  int b = blockIdx.x;
  for (int i = tid; i < 195; i += 256) {
    float v;
    if (i < 144) v = Wo_c[i];
    else if (i < 156) v = bo_c[i-144];
    else if (i < 192) v = W_out[i-156];
    else v = b_out[i-192];
    sw[i] = v;
  }
  if (tid < 160) {
    int h = tid / 40, j = tid - h*40;
    float v = 0.f;
    if (j < 39) v = momC[(b*4 + h)*40 + j] * mom_scale(j);
    smu[tid] = v;
  }
  __syncthreads();
  const float SC = 0.57735026918962584f;
  float st[15];
#pragma unroll
  for (int i = 0; i < 15; i++) st[i] = 0.f;
  float x3r[4][3];
#pragma unroll
  for (int r = 0; r < 4; r++) {
    int n = r*256 + tid;
    int t = b * N_ + n;
    float attn[E_];
#pragma unroll
    for (int h = 0; h < H_; h++) {
      float p0 = Qc[(b*4+h)*3072 + n] * SC;
      float p1 = Qc[(b*4+h)*3072 + 1024 + n] * SC;
      float p2 = Qc[(b*4+h)*3072 + 2048 + n] * SC;
      attn_eval(&smu[h*40], p0, p1, p2, &attn[h*3]);
    }
    float c12[E_];
#pragma unroll
    for (int e = 0; e < E_; e++) {
      float s = sw[144+e];
#pragma unroll
      for (int j = 0; j < E_; j++) s = fmaf(attn[j], sw[e*E_+j], s);
      c12[e] = s;
    }
    float co[3];
#pragma unroll
    for (int k = 0; k < 3; k++) {
      float s = sw[192+k];
#pragma unroll
      for (int e = 0; e < E_; e++) s = fmaf(c12[e], sw[156 + k*E_ + e], s);
      co[k] = s;
    }
    float x0 = x3[(size_t)t*3], x1 = x3[(size_t)t*3+1], x2 = x3[(size_t)t*3+2];
    x3r[r][0]=x0; x3r[r][1]=x1; x3r[r][2]=x2;
    float A0 = co[0]+x0, A1 = co[1]+x1, A2 = co[2]+x2;
    st[0]+=co[0]; st[1]+=co[1]; st[2]+=co[2];
    st[3]+=x0; st[4]+=x1; st[5]+=x2;
    st[6]=fmaf(x0,A0,st[6]);  st[7]=fmaf(x0,A1,st[7]);  st[8]=fmaf(x0,A2,st[8]);
    st[9]=fmaf(x1,A0,st[9]);  st[10]=fmaf(x1,A1,st[10]); st[11]=fmaf(x1,A2,st[11]);
    st[12]=fmaf(x2,A0,st[12]); st[13]=fmaf(x2,A1,st[13]); st[14]=fmaf(x2,A2,st[14]);
  }
#pragma unroll
  for (int i = 0; i < 15; i++) {
    st[i] += __shfl_down(st[i], 32); st[i] += __shfl_down(st[i], 16);
    st[i] += __shfl_down(st[i], 8);  st[i] += __shfl_down(st[i], 4);
    st[i] += __shfl_down(st[i], 2);  st[i] += __shfl_down(st[i], 1);
  }
  int wv = tid >> 6;
  if ((tid & 63) == 0) {
#pragma unroll
    for (int i = 0; i < 15; i++) sred[wv][i] = st[i];
  }
  __syncthreads();
  if (tid < 15) sstats[tid] = sred[0][tid] + sred[1][tid] + sred[2][tid] + sred[3][tid];
  __syncthreads();
  // ---- redundant uniform polar per thread ----
  const float* s = sstats;
  float invN = 1.0f / N_;
  float cB[3] = { s[3]*invN, s[4]*invN, s[5]*invN };
  float cA[3] = { (s[0]+s[3])*invN, (s[1]+s[4])*invN, (s[2]+s[5])*invN };
  float X[9];
#pragma unroll
  for (int i = 0; i < 3; i++)
#pragma unroll
    for (int j = 0; j < 3; j++)
      X[i*3+j] = s[6 + i*3 + j] - (float)N_ * cB[i] * cA[j];
  float fn = 0.f;
#pragma unroll
  for (int i = 0; i < 9; i++) fn += X[i]*X[i];
  float scl = rsqrtf(fn);
#pragma unroll
  for (int i = 0; i < 9; i++) X[i] *= scl;
  for (int it = 0; it < 24; it++) {
    float c00 =  X[4]*X[8]-X[5]*X[7];
    float c01 = -(X[3]*X[8]-X[5]*X[6]);
    float c02 =  X[3]*X[7]-X[4]*X[6];
    float c10 = -(X[1]*X[8]-X[2]*X[7]);
    float c11 =  X[0]*X[8]-X[2]*X[6];
    float c12_= -(X[0]*X[7]-X[1]*X[6]);
    float c20 =  X[1]*X[5]-X[2]*X[4];
    float c21 = -(X[0]*X[5]-X[2]*X[3]);
    float c22 =  X[0]*X[4]-X[1]*X[3];
    float det = X[0]*c00 + X[1]*c01 + X[2]*c02;
    float id = 0.5f / det;
    X[0]=0.5f*X[0]+c00*id; X[1]=0.5f*X[1]+c01*id; X[2]=0.5f*X[2]+c02*id;
    X[3]=0.5f*X[3]+c10*id; X[4]=0.5f*X[4]+c11*id; X[5]=0.5f*X[5]+c12_*id;
    X[6]=0.5f*X[6]+c20*id; X[7]=0.5f*X[7]+c21*id; X[8]=0.5f*X[8]+c22*id;
  }
  float tt[3];
#pragma unroll
  for (int k = 0; k < 3; k++) {
    float m = 0.f;
#pragma unroll
    for (int cc = 0; cc < 8; cc++) m += meanp[(16 + b)*128 + cc*16 + k];  // y mean comp k
    tt[k] = cA[k] - (cB[0]*X[k] + cB[1]*X[3+k] + cB[2]*X[6+k]) + m * invN;
  }
#pragma unroll
  for (int r = 0; r < 4; r++) {
    size_t t = (size_t)b * N_ + r*256 + tid;
#pragma unroll
    for (int k = 0; k < 3; k++) {
      float v = fmaf(x3r[r][0], X[k], fmaf(x3r[r][1], X[3+k], fmaf(x3r[r][2], X[6+k], tt[k])));
      out[t*3+k] = v;
    }
  }
}

extern "C" void kernel_launch(void* const* d_in, const int* in_sizes, int n_in,
                              void* d_out, int out_size, void* d_ws, size_t ws_size,
                              hipStream_t stream) {
  const float* x_orig = (const float*)d_in[0];
  const float* y_orig = (const float*)d_in[1];
  const float* W_in   = (const float*)d_in[2];
  const float* b_in   = (const float*)d_in[3];
  const float* Wqkv_s = (const float*)d_in[4];
  const float* bqkv_s = (const float*)d_in[5];
  const float* Wo_s   = (const float*)d_in[6];
  const float* bo_s   = (const float*)d_in[7];
  const float* Wqkv_c = (const float*)d_in[8];
  const float* bqkv_c = (const float*)d_in[9];
  const float* Wo_c   = (const float*)d_in[10];
  const float* bo_c   = (const float*)d_in[11];
  const float* W_out  = (const float*)d_in[12];
  const float* b_out  = (const float*)d_in[13];
  float* ws = (float*)d_ws;

  k_means<<<256, 128, 0, stream>>>(x_orig, y_orig, ws+OFF_MEANP, ws+OFF_MOMS);
  k_proj<<<256, 128, 0, stream>>>(x_orig, y_orig, ws+OFF_MEANP,
                                  W_in, b_in, Wqkv_s, bqkv_s,
                                  ws+OFF_X3, ws+OFF_QS, ws+OFF_MOMS);
  k_mid<<<256, 128, 0, stream>>>(ws+OFF_QS, ws+OFF_MOMS, Wo_s, bo_s, Wqkv_c, bqkv_c,
                                 ws+OFF_QC, ws+OFF_MOMC);
  k_fin<<<16, 256, 0, stream>>>(ws+OFF_QC, ws+OFF_MOMC, ws+OFF_X3, ws+OFF_MEANP,
                                Wo_c, bo_c, W_out, b_out, (float*)d_out);
}